// Round 2
// baseline (443.770 us; speedup 1.0000x reference)
//
#include <hip/hip_runtime.h>

// ---------------------------------------------------------------------------
// GPSLayer (GINE + global attention + FFN + 3x BatchNorm), MI355X gfx950.
// All float tensors are fp32; edge_index int32. Internally: bf16 MFMA compute
// with fp32 accumulation and fp32 intermediates.
// ---------------------------------------------------------------------------

#define N_NODES 16384
#define SEQL    512
#define NGRAPH  32
#define DIM     128
#define NHEAD   8
#define DHEAD   16
#define NEDGE   262144

typedef __bf16 bf16;
typedef __bf16 bf16x8 __attribute__((ext_vector_type(8)));
typedef __bf16 bf16x4 __attribute__((ext_vector_type(4)));
typedef float  f32x4  __attribute__((ext_vector_type(4)));

__device__ inline f32x4 mfma16(bf16x8 a, bf16x8 b, f32x4 c) {
  return __builtin_amdgcn_mfma_f32_16x16x32_bf16(a, b, c, 0, 0, 0);
}

// ---------------------------------------------------------------------------
// prep: fp32 weights -> bf16 (transposed where needed) + zero cnt + stats
// W layout (elements): G1T@0(16384) G2T@16384 IPT@32768(49152) OPT@81920(16384)
//                      F1T@98304(32768) F2T@131072(32768)  total 163840
// ---------------------------------------------------------------------------
__global__ __launch_bounds__(256) void prep_k(
    const float* __restrict__ gw1, const float* __restrict__ gw2,
    const float* __restrict__ ipw, const float* __restrict__ opw,
    const float* __restrict__ fw1, const float* __restrict__ fw2,
    bf16* __restrict__ W, int* __restrict__ cnt, float* __restrict__ stats)
{
  int i = blockIdx.x * 256 + threadIdx.x;
  if (i < 16384) {                       // G1T[n][k] = gin_w1[k][n]
    W[i] = (bf16)gw1[(i & 127) * 128 + (i >> 7)];
  } else if (i < 32768) {
    int j = i - 16384;                   // G2T
    W[i] = (bf16)gw2[(j & 127) * 128 + (j >> 7)];
  } else if (i < 81920) {                // IPT = in_proj_w rows (already [n][k])
    W[i] = (bf16)ipw[i - 32768];
  } else if (i < 98304) {                // OPT = out_proj_w rows
    W[i] = (bf16)opw[i - 81920];
  } else if (i < 131072) {               // F1T[n][k] = ff_w1[k][n], n<256,k<128
    int j = i - 98304;
    W[i] = (bf16)fw1[(j & 127) * 256 + (j >> 7)];
  } else if (i < 163840) {               // F2T[n][k] = ff_w2[k][n], n<128,k<256
    int j = i - 131072;
    W[i] = (bf16)fw2[(j & 255) * 128 + (j >> 8)];
  } else if (i < 163840 + 16384) {
    cnt[i - 163840] = 0;
  } else if (i < 163840 + 16384 + 768) {
    stats[i - 163840 - 16384] = 0.f;
  }
}

// ---------------------------------------------------------------------------
// edge bucketing by dst (counting sort -> CSR)
// ---------------------------------------------------------------------------
__global__ __launch_bounds__(256) void edge_count_k(const int* __restrict__ ei,
                                                    int* __restrict__ cnt)
{
  int e = blockIdx.x * 256 + threadIdx.x;
  if (e < NEDGE) atomicAdd(&cnt[ei[NEDGE + e]], 1);
}

__global__ __launch_bounds__(1024) void scan_k(const int* __restrict__ cnt,
                                               int* __restrict__ off,
                                               int* __restrict__ cur)
{
  __shared__ int part[1024];
  int t = threadIdx.x;
  int base = t * 16;
  int v[16];
  int s = 0;
#pragma unroll
  for (int j = 0; j < 16; ++j) { v[j] = s; s += cnt[base + j]; }
  part[t] = s;
  __syncthreads();
  for (int d = 1; d < 1024; d <<= 1) {
    int y = (t >= d) ? part[t - d] : 0;
    __syncthreads();
    part[t] += y;
    __syncthreads();
  }
  int bo = (t > 0) ? part[t - 1] : 0;
#pragma unroll
  for (int j = 0; j < 16; ++j) {
    int o = bo + v[j];
    off[base + j] = o;
    cur[base + j] = o;
  }
  if (t == 1023) off[16384] = bo + s;
}

__global__ __launch_bounds__(256) void edge_scatter_k(const int* __restrict__ ei,
                                                      int* __restrict__ cur,
                                                      int* __restrict__ elist)
{
  int e = blockIdx.x * 256 + threadIdx.x;
  if (e < NEDGE) {
    int d = ei[NEDGE + e];
    int p = atomicAdd(&cur[d], 1);
    elist[p] = e;
  }
}

// ---------------------------------------------------------------------------
// GINE aggregate: one wave per node. z = x + sum_{e->node} relu(x[src]+ea[e])
// lane handles 2 channels (float2), fp32 accumulate, fp32 store.
// ---------------------------------------------------------------------------
__global__ __launch_bounds__(256) void aggr_k(
    const float* __restrict__ x, const int* __restrict__ ei,
    const float* __restrict__ ea, const int* __restrict__ off,
    const int* __restrict__ elist, float* __restrict__ z)
{
  int node = blockIdx.x * 4 + (threadIdx.x >> 6);
  int lane = threadIdx.x & 63;
  int c = lane * 2;
  int o0 = off[node], o1 = off[node + 1];
  float a0 = 0.f, a1 = 0.f;
  for (int j = o0; j < o1; ++j) {
    int e = elist[j];
    int s = ei[e];
    float2 xe = *(const float2*)(x + (size_t)s * 128 + c);
    float2 ae = *(const float2*)(ea + (size_t)e * 128 + c);
    a0 += fmaxf(xe.x + ae.x, 0.f);
    a1 += fmaxf(xe.y + ae.y, 0.f);
  }
  float2 xn = *(const float2*)(x + (size_t)node * 128 + c);
  *(float2*)(z + (size_t)node * 128 + c) = make_float2(xn.x + a0, xn.y + a1);
}

// ---------------------------------------------------------------------------
// GEMM template. A [M][KCH*128] fp32 x Wt [NCH*128][KCH*128] (bf16, n-major)
// -> out. 256 blocks x 64 rows. 4 waves x (16 rows, 8 n-tiles) of 16x16x32.
// OUTMODE 0: fp32 out, ld = NCH*128.  OUTMODE 1: bf16 q/k/v split by nc.
// RESID: fp32 [M][128] added. STATS: column sum/sumsq -> stats (atomics).
// ---------------------------------------------------------------------------
template <int NCH, int KCH, bool RELU, int RESID, bool STATS, int OUTMODE>
__global__ __launch_bounds__(256) void gemm_k(
    const float* __restrict__ Aptr, const bf16* __restrict__ Wt,
    const float* __restrict__ bias, const float* __restrict__ resid,
    float* __restrict__ outF, bf16* __restrict__ oq, bf16* __restrict__ okk,
    bf16* __restrict__ ov, float* __restrict__ stats)
{
  constexpr int KIN = KCH * 128;
  constexpr int NLD = NCH * 128;
  __shared__ bf16 Alds[64][136];
  __shared__ bf16 Wlds[128][136];
  __shared__ float slds[256];
  int tid = threadIdx.x;
  int wave = tid >> 6, lane = tid & 63, quad = lane >> 4, l16 = lane & 15;
  int m0 = blockIdx.x * 64;
  if (STATS) slds[tid] = 0.f;

  for (int nc = 0; nc < NCH; ++nc) {
    f32x4 acc[8];
#pragma unroll
    for (int t = 0; t < 8; ++t) acc[t] = (f32x4){0.f, 0.f, 0.f, 0.f};
    for (int kc = 0; kc < KCH; ++kc) {
      if (!(nc == 0 && kc == 0)) __syncthreads();
      if (nc == 0 || KCH > 1) {
        int r = tid >> 5, c4 = (tid & 31) * 4;
#pragma unroll
        for (int it = 0; it < 8; ++it) {
          int row = r + it * 8;
          float4 vv = *(const float4*)(Aptr +
                       (size_t)(m0 + row) * KIN + kc * 128 + c4);
          *(bf16x4*)&Alds[row][c4] =
              (bf16x4){(bf16)vv.x, (bf16)vv.y, (bf16)vv.z, (bf16)vv.w};
        }
      }
      {
        int n = tid >> 1, ch = (tid & 1) * 64;
        const bf16* src = Wt + (size_t)(nc * 128 + n) * KIN + kc * 128 + ch;
        bf16* dst = &Wlds[n][ch];
#pragma unroll
        for (int j = 0; j < 8; ++j)
          *(bf16x8*)(dst + j * 8) = *(const bf16x8*)(src + j * 8);
      }
      __syncthreads();
#pragma unroll
      for (int kt = 0; kt < 4; ++kt) {
        bf16x8 af = *(const bf16x8*)&Alds[wave * 16 + l16][kt * 32 + quad * 8];
#pragma unroll
        for (int nt = 0; nt < 8; ++nt) {
          bf16x8 bfr = *(const bf16x8*)&Wlds[nt * 16 + l16][kt * 32 + quad * 8];
          acc[nt] = mfma16(af, bfr, acc[nt]);
        }
      }
    }
    // epilogue
    int rowb = m0 + wave * 16 + quad * 4;
#pragma unroll
    for (int nt = 0; nt < 8; ++nt) {
      int n = nt * 16 + l16;
      int gcol = nc * 128 + n;
      float bv = bias[gcol];
      float vals[4];
#pragma unroll
      for (int r = 0; r < 4; ++r) {
        float v = acc[nt][r] + bv;
        if (RELU) v = fmaxf(v, 0.f);
        if (RESID) v += resid[(size_t)(rowb + r) * 128 + n];
        vals[r] = v;
        if (OUTMODE == 0) {
          outF[(size_t)(rowb + r) * NLD + gcol] = v;
        } else {
          bf16* ob = (nc == 0) ? oq : ((nc == 1) ? okk : ov);
          ob[(size_t)(rowb + r) * 128 + n] = (bf16)v;
        }
      }
      if (STATS) {
        float s = vals[0] + vals[1] + vals[2] + vals[3];
        float q2 = vals[0] * vals[0] + vals[1] * vals[1] +
                   vals[2] * vals[2] + vals[3] * vals[3];
        s += __shfl_xor(s, 16);  s += __shfl_xor(s, 32);
        q2 += __shfl_xor(q2, 16); q2 += __shfl_xor(q2, 32);
        if (quad == 0) {
          atomicAdd(&slds[n * 2], s);
          atomicAdd(&slds[n * 2 + 1], q2);
        }
      }
    }
  }
  if (STATS) {
    __syncthreads();
    if (tid < 128) {
      atomicAdd(&stats[tid], slds[tid * 2]);
      atomicAdd(&stats[128 + tid], slds[tid * 2 + 1]);
    }
  }
}

// ---------------------------------------------------------------------------
// Attention: block = (graph, head, q-half). 4 waves, each 4 q-tiles of 16 rows.
// S^T = K*Q^T (dh=16 zero-padded to K=32), row-softmax via cross-quad shuffles,
// P -> LDS (bf16, quartered), O^T = V^T * P^T, fp32 out [N][128].
// ---------------------------------------------------------------------------
__global__ __launch_bounds__(256) void attn_k(
    const bf16* __restrict__ qg, const bf16* __restrict__ kg,
    const bf16* __restrict__ vg, float* __restrict__ og)
{
  __shared__ bf16 Klds[512][16];
  __shared__ bf16 Vlds[16][520];
  __shared__ bf16 Plds[4][16][136];
  int b = blockIdx.x;
  int half = b & 1, hh = (b >> 1) & 7, g = b >> 4;
  int tid = threadIdx.x;
  const size_t gbase = (size_t)g * 512 * 128 + hh * 16;
  for (int r = tid; r < 512; r += 256) {
    const bf16* src = kg + gbase + (size_t)r * 128;
    *(bf16x8*)&Klds[r][0] = *(const bf16x8*)src;
    *(bf16x8*)&Klds[r][8] = *(const bf16x8*)(src + 8);
  }
  for (int r = tid; r < 512; r += 256) {
    const bf16* src = vg + gbase + (size_t)r * 128;
#pragma unroll
    for (int d = 0; d < 16; ++d) Vlds[d][r] = src[d];
  }
  __syncthreads();
  int wave = tid >> 6, lane = tid & 63, quad = lane >> 4, l16 = lane & 15;
  const bf16x8 z8 = {};
  for (int it = 0; it < 4; ++it) {
    int qt = half * 16 + it * 4 + wave;
    bf16x8 qf = z8;
    if (quad < 2)
      qf = *(const bf16x8*)(qg + gbase + (size_t)(qt * 16 + l16) * 128 + quad * 8);
    f32x4 S[32];
#pragma unroll
    for (int jt = 0; jt < 32; ++jt) {
      bf16x8 kf = z8;
      if (quad < 2) kf = *(const bf16x8*)&Klds[jt * 16 + l16][quad * 8];
      S[jt] = mfma16(kf, qf, (f32x4){0.f, 0.f, 0.f, 0.f});
    }
    // softmax over j (rows of S^T) for query col = l16; scale 1/sqrt(16)=0.25
    float mx = -1e30f;
#pragma unroll
    for (int jt = 0; jt < 32; ++jt)
#pragma unroll
      for (int r = 0; r < 4; ++r) mx = fmaxf(mx, S[jt][r]);
    mx = fmaxf(mx, __shfl_xor(mx, 16));
    mx = fmaxf(mx, __shfl_xor(mx, 32));
    float sm = 0.f;
#pragma unroll
    for (int jt = 0; jt < 32; ++jt)
#pragma unroll
      for (int r = 0; r < 4; ++r) {
        float e = __expf((S[jt][r] - mx) * 0.25f);
        S[jt][r] = e;
        sm += e;
      }
    sm += __shfl_xor(sm, 16);
    sm += __shfl_xor(sm, 32);
    float rinv = 1.f / sm;
    f32x4 O = (f32x4){0.f, 0.f, 0.f, 0.f};
#pragma unroll
    for (int qd = 0; qd < 4; ++qd) {
#pragma unroll
      for (int jt2 = 0; jt2 < 8; ++jt2)
#pragma unroll
        for (int r = 0; r < 4; ++r)
          Plds[wave][l16][jt2 * 16 + quad * 4 + r] =
              (bf16)(S[qd * 8 + jt2][r] * rinv);
#pragma unroll
      for (int kt = 0; kt < 4; ++kt) {
        bf16x8 pf = *(const bf16x8*)&Plds[wave][l16][kt * 32 + quad * 8];
        bf16x8 vf = *(const bf16x8*)&Vlds[l16][qd * 128 + kt * 32 + quad * 8];
        O = mfma16(vf, pf, O);
      }
    }
    *(float4*)(og + (size_t)(g * 512 + qt * 16 + l16) * 128 + hh * 16 + quad * 4) =
        make_float4(O[0], O[1], O[2], O[3]);
  }
}

// ---------------------------------------------------------------------------
// combine: h = bn1l(hl) + bn1a(ha)
// ---------------------------------------------------------------------------
__global__ __launch_bounds__(256) void combine_k(
    const float* __restrict__ hl, const float* __restrict__ ha,
    const float* __restrict__ stats,
    const float* __restrict__ g1, const float* __restrict__ b1,
    const float* __restrict__ g2, const float* __restrict__ b2,
    float* __restrict__ h)
{
  __shared__ float sc1[128], sh1[128], sc2[128], sh2[128];
  int tid = threadIdx.x;
  if (tid < 128) {
    const float inv = 1.f / 16384.f;
    float mu = stats[tid] * inv;
    float var = stats[128 + tid] * inv - mu * mu;
    float s = g1[tid] * rsqrtf(var + 1e-5f);
    sc1[tid] = s; sh1[tid] = b1[tid] - mu * s;
    mu = stats[256 + tid] * inv;
    var = stats[384 + tid] * inv - mu * mu;
    s = g2[tid] * rsqrtf(var + 1e-5f);
    sc2[tid] = s; sh2[tid] = b2[tid] - mu * s;
  }
  __syncthreads();
  size_t i = ((size_t)blockIdx.x * 256 + tid) * 4;
  int c = (int)(i & 127);
  float4 a = *(const float4*)(hl + i);
  float4 bb = *(const float4*)(ha + i);
  float4 o;
  o.x = a.x * sc1[c] + sh1[c] + bb.x * sc2[c] + sh2[c];
  o.y = a.y * sc1[c + 1] + sh1[c + 1] + bb.y * sc2[c + 1] + sh2[c + 1];
  o.z = a.z * sc1[c + 2] + sh1[c + 2] + bb.z * sc2[c + 2] + sh2[c + 2];
  o.w = a.w * sc1[c + 3] + sh1[c + 3] + bb.w * sc2[c + 3] + sh2[c + 3];
  *(float4*)(h + i) = o;
}

// ---------------------------------------------------------------------------
// apply: out = bn2(h2)  (fp32 output)
// ---------------------------------------------------------------------------
__global__ __launch_bounds__(256) void apply_k(
    const float* __restrict__ h2, const float* __restrict__ stats,
    const float* __restrict__ g, const float* __restrict__ b,
    float* __restrict__ out)
{
  __shared__ float sc[128], sh[128];
  int tid = threadIdx.x;
  if (tid < 128) {
    const float inv = 1.f / 16384.f;
    float mu = stats[512 + tid] * inv;
    float var = stats[640 + tid] * inv - mu * mu;
    float s = g[tid] * rsqrtf(var + 1e-5f);
    sc[tid] = s; sh[tid] = b[tid] - mu * s;
  }
  __syncthreads();
  size_t i = ((size_t)blockIdx.x * 256 + tid) * 4;
  int c = (int)(i & 127);
  float4 a = *(const float4*)(h2 + i);
  float4 o;
  o.x = a.x * sc[c] + sh[c];
  o.y = a.y * sc[c + 1] + sh[c + 1];
  o.z = a.z * sc[c + 2] + sh[c + 2];
  o.w = a.w * sc[c + 3] + sh[c + 3];
  *(float4*)(out + i) = o;
}

// ---------------------------------------------------------------------------
extern "C" void kernel_launch(void* const* d_in, const int* in_sizes, int n_in,
                              void* d_out, int out_size, void* d_ws, size_t ws_size,
                              hipStream_t stream)
{
  (void)in_sizes; (void)n_in; (void)out_size; (void)ws_size;
  const float* x      = (const float*)d_in[0];
  const int*   ei     = (const int*)d_in[1];
  const float* ea     = (const float*)d_in[2];
  const float* gw1    = (const float*)d_in[3];
  const float* gb1    = (const float*)d_in[4];
  const float* gw2    = (const float*)d_in[5];
  const float* gb2    = (const float*)d_in[6];
  const float* bn1l_g = (const float*)d_in[7];
  const float* bn1l_b = (const float*)d_in[8];
  const float* ipw    = (const float*)d_in[9];
  const float* ipb    = (const float*)d_in[10];
  const float* opw    = (const float*)d_in[11];
  const float* opb    = (const float*)d_in[12];
  const float* bn1a_g = (const float*)d_in[13];
  const float* bn1a_b = (const float*)d_in[14];
  const float* fw1    = (const float*)d_in[15];
  const float* fb1    = (const float*)d_in[16];
  const float* fw2    = (const float*)d_in[17];
  const float* fb2    = (const float*)d_in[18];
  const float* bn2_g  = (const float*)d_in[19];
  const float* bn2_b  = (const float*)d_in[20];

  char* ws = (char*)d_ws;
  bf16*  W     = (bf16*)(ws + 0);          // 163840 bf16 = 327680 B
  float* stats = (float*)(ws + 327680);    // 768 floats
  int*   cnt   = (int*)(ws + 330752);      // 16384
  int*   off   = (int*)(ws + 396288);      // 16385
  int*   cur   = (int*)(ws + 461952);      // 16384
  int*   elist = (int*)(ws + 527488);      // 262144
  const size_t MB = 1048576;
  float* z   = (float*)(ws + 2 * MB);      // 8MB  (reused by ff1 lo)
  float* t1  = (float*)(ws + 10 * MB);     // 8MB  (reused by ff1 hi)
  float* hl  = (float*)(ws + 18 * MB);     // 8MB
  bf16*  qb  = (bf16*)(ws + 26 * MB);      // 4MB
  bf16*  kb  = (bf16*)(ws + 30 * MB);      // 4MB
  bf16*  vb  = (bf16*)(ws + 34 * MB);      // 4MB
  float* ob  = (float*)(ws + 38 * MB);     // 8MB  (reused by h2)
  float* ha  = (float*)(ws + 46 * MB);     // 8MB
  float* hb  = (float*)(ws + 54 * MB);     // 8MB  -> total 62MB
  float* ff1 = z;                          // [N][256] spans z+t1 (16MB)
  float* h2  = ob;
  float* out = (float*)d_out;

  prep_k<<<708, 256, 0, stream>>>(gw1, gw2, ipw, opw, fw1, fw2, W, cnt, stats);
  edge_count_k<<<1024, 256, 0, stream>>>(ei, cnt);
  scan_k<<<1, 1024, 0, stream>>>(cnt, off, cur);
  edge_scatter_k<<<1024, 256, 0, stream>>>(ei, cur, elist);
  aggr_k<<<4096, 256, 0, stream>>>(x, ei, ea, off, elist, z);
  // t1 = relu(z @ gin_w1 + b1)
  gemm_k<1, 1, true, 0, false, 0><<<256, 256, 0, stream>>>(
      z, W + 0, gb1, nullptr, t1, nullptr, nullptr, nullptr, nullptr);
  // hl = t1 @ gin_w2 + b2 + x   (+bn1l stats)
  gemm_k<1, 1, false, 1, true, 0><<<256, 256, 0, stream>>>(
      t1, W + 16384, gb2, x, hl, nullptr, nullptr, nullptr, stats + 0);
  // q,k,v = x @ in_proj_w.T + b  (bf16 out)
  gemm_k<3, 1, false, 0, false, 1><<<256, 256, 0, stream>>>(
      x, W + 32768, ipb, nullptr, nullptr, qb, kb, vb, nullptr);
  attn_k<<<512, 256, 0, stream>>>(qb, kb, vb, ob);
  // ha = o @ out_proj_w.T + b + x   (+bn1a stats)
  gemm_k<1, 1, false, 1, true, 0><<<256, 256, 0, stream>>>(
      ob, W + 81920, opb, x, ha, nullptr, nullptr, nullptr, stats + 256);
  combine_k<<<2048, 256, 0, stream>>>(hl, ha, stats, bn1l_g, bn1l_b, bn1a_g, bn1a_b, hb);
  // ff1 = relu(h @ ff_w1 + b1)   [N][256]
  gemm_k<2, 1, true, 0, false, 0><<<256, 256, 0, stream>>>(
      hb, W + 98304, fb1, nullptr, ff1, nullptr, nullptr, nullptr, nullptr);
  // h2 = ff1 @ ff_w2 + b2 + h   (+bn2 stats)
  gemm_k<1, 2, false, 1, true, 0><<<256, 256, 0, stream>>>(
      ff1, W + 131072, fb2, hb, h2, nullptr, nullptr, nullptr, stats + 512);
  apply_k<<<2048, 256, 0, stream>>>(h2, stats, bn2_g, bn2_b, out);
}

// Round 4
// 428.796 us; speedup vs baseline: 1.0349x; 1.0349x over previous
//
#include <hip/hip_runtime.h>

// ---------------------------------------------------------------------------
// GPSLayer (GINE + global attention + FFN + 3x BatchNorm), MI355X gfx950.
// fp32 in/out; internal bf16 MFMA with fp32 accumulation.
// ---------------------------------------------------------------------------

#define N_NODES 16384
#define SEQL    512
#define NGRAPH  32
#define DIM     128
#define NHEAD   8
#define DHEAD   16
#define NEDGE   262144

typedef __bf16 bf16;
typedef __bf16 bf16x8 __attribute__((ext_vector_type(8)));
typedef __bf16 bf16x4 __attribute__((ext_vector_type(4)));
typedef float  f32x4  __attribute__((ext_vector_type(4)));

__device__ inline f32x4 mfma16(bf16x8 a, bf16x8 b, f32x4 c) {
  return __builtin_amdgcn_mfma_f32_16x16x32_bf16(a, b, c, 0, 0, 0);
}

// ---------------------------------------------------------------------------
// prep: fp32 weights -> bf16 (transposed where needed) + zero cnt + stats
// W layout (elements): G1T@0(16384) G2T@16384 IPT@32768(49152) OPT@81920(16384)
//                      F1T@98304(32768) F2T@131072(32768)  total 163840
// ---------------------------------------------------------------------------
__global__ __launch_bounds__(256) void prep_k(
    const float* __restrict__ gw1, const float* __restrict__ gw2,
    const float* __restrict__ ipw, const float* __restrict__ opw,
    const float* __restrict__ fw1, const float* __restrict__ fw2,
    bf16* __restrict__ W, int* __restrict__ cnt, float* __restrict__ stats)
{
  int i = blockIdx.x * 256 + threadIdx.x;
  if (i < 16384) {                       // G1T[n][k] = gin_w1[k][n]
    W[i] = (bf16)gw1[(i & 127) * 128 + (i >> 7)];
  } else if (i < 32768) {
    int j = i - 16384;                   // G2T
    W[i] = (bf16)gw2[(j & 127) * 128 + (j >> 7)];
  } else if (i < 81920) {                // IPT = in_proj_w rows (already [n][k])
    W[i] = (bf16)ipw[i - 32768];
  } else if (i < 98304) {                // OPT = out_proj_w rows
    W[i] = (bf16)opw[i - 81920];
  } else if (i < 131072) {               // F1T[n][k] = ff_w1[k][n], n<256,k<128
    int j = i - 98304;
    W[i] = (bf16)fw1[(j & 127) * 256 + (j >> 7)];
  } else if (i < 163840) {               // F2T[n][k] = ff_w2[k][n], n<128,k<256
    int j = i - 131072;
    W[i] = (bf16)fw2[(j & 255) * 128 + (j >> 8)];
  } else if (i < 163840 + 16384) {
    cnt[i - 163840] = 0;
  } else if (i < 163840 + 16384 + 768) {
    stats[i - 163840 - 16384] = 0.f;
  }
}

// ---------------------------------------------------------------------------
// edge bucketing by dst (counting sort -> CSR, payload = (src, edge_id))
// ---------------------------------------------------------------------------
__global__ __launch_bounds__(256) void edge_count_k(const int* __restrict__ ei,
                                                    int* __restrict__ cnt)
{
  int e = blockIdx.x * 256 + threadIdx.x;
  if (e < NEDGE) atomicAdd(&cnt[ei[NEDGE + e]], 1);
}

__global__ __launch_bounds__(1024) void scan_k(const int* __restrict__ cnt,
                                               int* __restrict__ off,
                                               int* __restrict__ cur)
{
  __shared__ int part[1024];
  int t = threadIdx.x;
  int base = t * 16;
  int v[16];
  int s = 0;
#pragma unroll
  for (int j = 0; j < 16; ++j) { v[j] = s; s += cnt[base + j]; }
  part[t] = s;
  __syncthreads();
  for (int d = 1; d < 1024; d <<= 1) {
    int y = (t >= d) ? part[t - d] : 0;
    __syncthreads();
    part[t] += y;
    __syncthreads();
  }
  int bo = (t > 0) ? part[t - 1] : 0;
#pragma unroll
  for (int j = 0; j < 16; ++j) {
    int o = bo + v[j];
    off[base + j] = o;
    cur[base + j] = o;
  }
  if (t == 1023) off[16384] = bo + s;
}

__global__ __launch_bounds__(256) void edge_scatter_k(const int* __restrict__ ei,
                                                      int* __restrict__ cur,
                                                      int2* __restrict__ se)
{
  int e = blockIdx.x * 256 + threadIdx.x;
  if (e < NEDGE) {
    int s = ei[e];
    int d = ei[NEDGE + e];
    int p = atomicAdd(&cur[d], 1);
    se[p] = make_int2(s, e);
  }
}

// ---------------------------------------------------------------------------
// GINE aggregate: one wave per node. z = x + sum_{e->node} relu(x[src]+ea[e])
// lane = 2 channels (float2). 4x unrolled: 4 independent (src,e) chains in
// flight -> 8 independent 512B row reads per group.
// ---------------------------------------------------------------------------
__global__ __launch_bounds__(256) void aggr_k(
    const float* __restrict__ x, const float* __restrict__ ea,
    const int* __restrict__ off, const int2* __restrict__ se,
    float* __restrict__ z)
{
  int node = blockIdx.x * 4 + (threadIdx.x >> 6);
  int lane = threadIdx.x & 63;
  int c = lane * 2;
  int o0 = off[node], o1 = off[node + 1];
  float a0 = 0.f, a1 = 0.f;
  int j = o0;
  for (; j + 4 <= o1; j += 4) {
    int2 p0 = se[j], p1 = se[j + 1], p2 = se[j + 2], p3 = se[j + 3];
    float2 x0 = *(const float2*)(x + (size_t)p0.x * 128 + c);
    float2 e0 = *(const float2*)(ea + (size_t)p0.y * 128 + c);
    float2 x1 = *(const float2*)(x + (size_t)p1.x * 128 + c);
    float2 e1 = *(const float2*)(ea + (size_t)p1.y * 128 + c);
    float2 x2 = *(const float2*)(x + (size_t)p2.x * 128 + c);
    float2 e2 = *(const float2*)(ea + (size_t)p2.y * 128 + c);
    float2 x3 = *(const float2*)(x + (size_t)p3.x * 128 + c);
    float2 e3 = *(const float2*)(ea + (size_t)p3.y * 128 + c);
    a0 += fmaxf(x0.x + e0.x, 0.f) + fmaxf(x1.x + e1.x, 0.f) +
          fmaxf(x2.x + e2.x, 0.f) + fmaxf(x3.x + e3.x, 0.f);
    a1 += fmaxf(x0.y + e0.y, 0.f) + fmaxf(x1.y + e1.y, 0.f) +
          fmaxf(x2.y + e2.y, 0.f) + fmaxf(x3.y + e3.y, 0.f);
  }
  for (; j < o1; ++j) {
    int2 p = se[j];
    float2 xe = *(const float2*)(x + (size_t)p.x * 128 + c);
    float2 ae = *(const float2*)(ea + (size_t)p.y * 128 + c);
    a0 += fmaxf(xe.x + ae.x, 0.f);
    a1 += fmaxf(xe.y + ae.y, 0.f);
  }
  float2 xn = *(const float2*)(x + (size_t)node * 128 + c);
  *(float2*)(z + (size_t)node * 128 + c) = make_float2(xn.x + a0, xn.y + a1);
}

// ---------------------------------------------------------------------------
// GEMM template. A [M][KCH*128] fp32 x Wt [NCH*128][KCH*128] (bf16, n-major).
// 512 blocks x 32 rows, 256 threads = 4 waves; wave (rg, chalf) computes
// 16 rows x 64 cols (4 n-tiles of 16x16x32). 2 blocks/CU.
// OUTMODE 0: fp32 out, ld = NCH*128.  OUTMODE 1: bf16 q/k/v split by nc.
// RESID: fp32 [M][128] added. STATS: column sum/sumsq -> stats (atomics).
// ---------------------------------------------------------------------------
template <int NCH, int KCH, bool RELU, int RESID, bool STATS, int OUTMODE>
__global__ __launch_bounds__(256) void gemm_k(
    const float* __restrict__ Aptr, const bf16* __restrict__ Wt,
    const float* __restrict__ bias, const float* __restrict__ resid,
    float* __restrict__ outF, bf16* __restrict__ oq, bf16* __restrict__ okk,
    bf16* __restrict__ ov, float* __restrict__ stats)
{
  constexpr int KIN = KCH * 128;
  constexpr int NLD = NCH * 128;
  __shared__ bf16 Alds[32][136];
  __shared__ bf16 Wlds[128][136];
  __shared__ float slds[256];
  int tid = threadIdx.x;
  int wave = tid >> 6, lane = tid & 63, quad = lane >> 4, l16 = lane & 15;
  int rg = wave >> 1, chalf = wave & 1;
  int m0 = blockIdx.x * 32;
  if (STATS) slds[tid] = 0.f;

  for (int nc = 0; nc < NCH; ++nc) {
    f32x4 acc[4];
#pragma unroll
    for (int t = 0; t < 4; ++t) acc[t] = (f32x4){0.f, 0.f, 0.f, 0.f};
    for (int kc = 0; kc < KCH; ++kc) {
      if (!(nc == 0 && kc == 0)) __syncthreads();
      if (nc == 0 || KCH > 1) {
        int r = tid >> 3, c16 = (tid & 7) * 16;
        const float* src = Aptr + (size_t)(m0 + r) * KIN + kc * 128 + c16;
        float4 v0 = *(const float4*)(src);
        float4 v1 = *(const float4*)(src + 4);
        float4 v2 = *(const float4*)(src + 8);
        float4 v3 = *(const float4*)(src + 12);
        *(bf16x8*)&Alds[r][c16] =
            (bf16x8){(bf16)v0.x, (bf16)v0.y, (bf16)v0.z, (bf16)v0.w,
                     (bf16)v1.x, (bf16)v1.y, (bf16)v1.z, (bf16)v1.w};
        *(bf16x8*)&Alds[r][c16 + 8] =
            (bf16x8){(bf16)v2.x, (bf16)v2.y, (bf16)v2.z, (bf16)v2.w,
                     (bf16)v3.x, (bf16)v3.y, (bf16)v3.z, (bf16)v3.w};
      }
      {
        int n = tid >> 1, ch = (tid & 1) * 64;
        const bf16* src = Wt + (size_t)(nc * 128 + n) * KIN + kc * 128 + ch;
        bf16* dst = &Wlds[n][ch];
#pragma unroll
        for (int j = 0; j < 8; ++j)
          *(bf16x8*)(dst + j * 8) = *(const bf16x8*)(src + j * 8);
      }
      __syncthreads();
#pragma unroll
      for (int kt = 0; kt < 4; ++kt) {
        bf16x8 af = *(const bf16x8*)&Alds[rg * 16 + l16][kt * 32 + quad * 8];
#pragma unroll
        for (int nt = 0; nt < 4; ++nt) {
          bf16x8 bfr =
              *(const bf16x8*)&Wlds[chalf * 64 + nt * 16 + l16][kt * 32 + quad * 8];
          acc[nt] = mfma16(af, bfr, acc[nt]);
        }
      }
    }
    // epilogue
    int rowb = m0 + rg * 16 + quad * 4;
#pragma unroll
    for (int nt = 0; nt < 4; ++nt) {
      int n = chalf * 64 + nt * 16 + l16;
      int gcol = nc * 128 + n;
      float bv = bias[gcol];
      float vals[4];
#pragma unroll
      for (int r = 0; r < 4; ++r) {
        float v = acc[nt][r] + bv;
        if (RELU) v = fmaxf(v, 0.f);
        if (RESID) v += resid[(size_t)(rowb + r) * 128 + n];
        vals[r] = v;
        if (OUTMODE == 0) {
          outF[(size_t)(rowb + r) * NLD + gcol] = v;
        } else {
          bf16* ob = (nc == 0) ? oq : ((nc == 1) ? okk : ov);
          ob[(size_t)(rowb + r) * 128 + n] = (bf16)v;
        }
      }
      if (STATS) {
        float s = vals[0] + vals[1] + vals[2] + vals[3];
        float q2 = vals[0] * vals[0] + vals[1] * vals[1] +
                   vals[2] * vals[2] + vals[3] * vals[3];
        s += __shfl_xor(s, 16);  s += __shfl_xor(s, 32);
        q2 += __shfl_xor(q2, 16); q2 += __shfl_xor(q2, 32);
        if (quad == 0) {
          atomicAdd(&slds[n * 2], s);
          atomicAdd(&slds[n * 2 + 1], q2);
        }
      }
    }
  }
  if (STATS) {
    __syncthreads();
    if (tid < 128) {
      atomicAdd(&stats[tid], slds[tid * 2]);
      atomicAdd(&stats[128 + tid], slds[tid * 2 + 1]);
    }
  }
}

// ---------------------------------------------------------------------------
// Attention: block = (graph, head, q-half). 4 waves, each 4 q-tiles of 16 rows.
// S^T = K*Q^T (dh=16 zero-padded to K=32), row-softmax via cross-quad shuffles,
// P -> LDS (bf16, quartered), O^T = V^T * P^T, fp32 out [N][128].
// ---------------------------------------------------------------------------
__global__ __launch_bounds__(256) void attn_k(
    const bf16* __restrict__ qg, const bf16* __restrict__ kg,
    const bf16* __restrict__ vg, float* __restrict__ og)
{
  __shared__ bf16 Klds[512][16];
  __shared__ bf16 Vlds[16][520];
  __shared__ bf16 Plds[4][16][136];
  int b = blockIdx.x;
  int half = b & 1, hh = (b >> 1) & 7, g = b >> 4;
  int tid = threadIdx.x;
  const size_t gbase = (size_t)g * 512 * 128 + hh * 16;
  for (int r = tid; r < 512; r += 256) {
    const bf16* src = kg + gbase + (size_t)r * 128;
    *(bf16x8*)&Klds[r][0] = *(const bf16x8*)src;
    *(bf16x8*)&Klds[r][8] = *(const bf16x8*)(src + 8);
  }
  for (int r = tid; r < 512; r += 256) {
    const bf16* src = vg + gbase + (size_t)r * 128;
#pragma unroll
    for (int d = 0; d < 16; ++d) Vlds[d][r] = src[d];
  }
  __syncthreads();
  int wave = tid >> 6, lane = tid & 63, quad = lane >> 4, l16 = lane & 15;
  const bf16x8 z8 = {};
  for (int it = 0; it < 4; ++it) {
    int qt = half * 16 + it * 4 + wave;
    bf16x8 qf = z8;
    if (quad < 2)
      qf = *(const bf16x8*)(qg + gbase + (size_t)(qt * 16 + l16) * 128 + quad * 8);
    f32x4 S[32];
#pragma unroll
    for (int jt = 0; jt < 32; ++jt) {
      bf16x8 kf = z8;
      if (quad < 2) kf = *(const bf16x8*)&Klds[jt * 16 + l16][quad * 8];
      S[jt] = mfma16(kf, qf, (f32x4){0.f, 0.f, 0.f, 0.f});
    }
    float mx = -1e30f;
#pragma unroll
    for (int jt = 0; jt < 32; ++jt)
#pragma unroll
      for (int r = 0; r < 4; ++r) mx = fmaxf(mx, S[jt][r]);
    mx = fmaxf(mx, __shfl_xor(mx, 16));
    mx = fmaxf(mx, __shfl_xor(mx, 32));
    float sm = 0.f;
#pragma unroll
    for (int jt = 0; jt < 32; ++jt)
#pragma unroll
      for (int r = 0; r < 4; ++r) {
        float e = __expf((S[jt][r] - mx) * 0.25f);
        S[jt][r] = e;
        sm += e;
      }
    sm += __shfl_xor(sm, 16);
    sm += __shfl_xor(sm, 32);
    float rinv = 1.f / sm;
    f32x4 O = (f32x4){0.f, 0.f, 0.f, 0.f};
#pragma unroll
    for (int qd = 0; qd < 4; ++qd) {
#pragma unroll
      for (int jt2 = 0; jt2 < 8; ++jt2)
#pragma unroll
        for (int r = 0; r < 4; ++r)
          Plds[wave][l16][jt2 * 16 + quad * 4 + r] =
              (bf16)(S[qd * 8 + jt2][r] * rinv);
#pragma unroll
      for (int kt = 0; kt < 4; ++kt) {
        bf16x8 pf = *(const bf16x8*)&Plds[wave][l16][kt * 32 + quad * 8];
        bf16x8 vf = *(const bf16x8*)&Vlds[l16][qd * 128 + kt * 32 + quad * 8];
        O = mfma16(vf, pf, O);
      }
    }
    *(float4*)(og + (size_t)(g * 512 + qt * 16 + l16) * 128 + hh * 16 + quad * 4) =
        make_float4(O[0], O[1], O[2], O[3]);
  }
}

// ---------------------------------------------------------------------------
// combine: h = bn1l(hl) + bn1a(ha)
// ---------------------------------------------------------------------------
__global__ __launch_bounds__(256) void combine_k(
    const float* __restrict__ hl, const float* __restrict__ ha,
    const float* __restrict__ stats,
    const float* __restrict__ g1, const float* __restrict__ b1,
    const float* __restrict__ g2, const float* __restrict__ b2,
    float* __restrict__ h)
{
  __shared__ float sc1[128], sh1[128], sc2[128], sh2[128];
  int tid = threadIdx.x;
  if (tid < 128) {
    const float inv = 1.f / 16384.f;
    float mu = stats[tid] * inv;
    float var = stats[128 + tid] * inv - mu * mu;
    float s = g1[tid] * rsqrtf(var + 1e-5f);
    sc1[tid] = s; sh1[tid] = b1[tid] - mu * s;
    mu = stats[256 + tid] * inv;
    var = stats[384 + tid] * inv - mu * mu;
    s = g2[tid] * rsqrtf(var + 1e-5f);
    sc2[tid] = s; sh2[tid] = b2[tid] - mu * s;
  }
  __syncthreads();
  size_t i = ((size_t)blockIdx.x * 256 + tid) * 4;
  int c = (int)(i & 127);
  float4 a = *(const float4*)(hl + i);
  float4 bb = *(const float4*)(ha + i);
  float4 o;
  o.x = a.x * sc1[c] + sh1[c] + bb.x * sc2[c] + sh2[c];
  o.y = a.y * sc1[c + 1] + sh1[c + 1] + bb.y * sc2[c + 1] + sh2[c + 1];
  o.z = a.z * sc1[c + 2] + sh1[c + 2] + bb.z * sc2[c + 2] + sh2[c + 2];
  o.w = a.w * sc1[c + 3] + sh1[c + 3] + bb.w * sc2[c + 3] + sh2[c + 3];
  *(float4*)(h + i) = o;
}

// ---------------------------------------------------------------------------
// apply: out = bn2(h2)  (fp32 output)
// ---------------------------------------------------------------------------
__global__ __launch_bounds__(256) void apply_k(
    const float* __restrict__ h2, const float* __restrict__ stats,
    const float* __restrict__ g, const float* __restrict__ b,
    float* __restrict__ out)
{
  __shared__ float sc[128], sh[128];
  int tid = threadIdx.x;
  if (tid < 128) {
    const float inv = 1.f / 16384.f;
    float mu = stats[512 + tid] * inv;
    float var = stats[640 + tid] * inv - mu * mu;
    float s = g[tid] * rsqrtf(var + 1e-5f);
    sc[tid] = s; sh[tid] = b[tid] - mu * s;
  }
  __syncthreads();
  size_t i = ((size_t)blockIdx.x * 256 + tid) * 4;
  int c = (int)(i & 127);
  float4 a = *(const float4*)(h2 + i);
  float4 o;
  o.x = a.x * sc[c] + sh[c];
  o.y = a.y * sc[c + 1] + sh[c + 1];
  o.z = a.z * sc[c + 2] + sh[c + 2];
  o.w = a.w * sc[c + 3] + sh[c + 3];
  *(float4*)(out + i) = o;
}

// ---------------------------------------------------------------------------
extern "C" void kernel_launch(void* const* d_in, const int* in_sizes, int n_in,
                              void* d_out, int out_size, void* d_ws, size_t ws_size,
                              hipStream_t stream)
{
  (void)in_sizes; (void)n_in; (void)out_size; (void)ws_size;
  const float* x      = (const float*)d_in[0];
  const int*   ei     = (const int*)d_in[1];
  const float* ea     = (const float*)d_in[2];
  const float* gw1    = (const float*)d_in[3];
  const float* gb1    = (const float*)d_in[4];
  const float* gw2    = (const float*)d_in[5];
  const float* gb2    = (const float*)d_in[6];
  const float* bn1l_g = (const float*)d_in[7];
  const float* bn1l_b = (const float*)d_in[8];
  const float* ipw    = (const float*)d_in[9];
  const float* ipb    = (const float*)d_in[10];
  const float* opw    = (const float*)d_in[11];
  const float* opb    = (const float*)d_in[12];
  const float* bn1a_g = (const float*)d_in[13];
  const float* bn1a_b = (const float*)d_in[14];
  const float* fw1    = (const float*)d_in[15];
  const float* fb1    = (const float*)d_in[16];
  const float* fw2    = (const float*)d_in[17];
  const float* fb2    = (const float*)d_in[18];
  const float* bn2_g  = (const float*)d_in[19];
  const float* bn2_b  = (const float*)d_in[20];

  // ---- workspace map (all offsets byte-exact, verified non-overlapping) ----
  // [0,320K)      W bf16 weights        (327680)
  // [320K,+3K)    stats 768 f32         (327680..330752)
  // [384K,448K)   cnt   16384 i32
  // [448K,512K+4) off   16385 i32
  // [576K,640K)   cur   16384 i32
  // [640K,2.625M) se    262144 int2
  // [3M,11M)   z  | [11M,19M) hl | [19M,23M) qb | [23M,27M) kb | [27M,31M) vb
  // [31M,39M)  ob | [39M,47M) ha | [47M,55M) hb        (total 55MB)
  char* ws = (char*)d_ws;
  const size_t KB = 1024, MB = 1048576;
  bf16*  W     = (bf16*)(ws + 0);
  float* stats = (float*)(ws + 320 * KB);
  int*   cnt   = (int*)(ws + 384 * KB);
  int*   off   = (int*)(ws + 448 * KB);
  int*   cur   = (int*)(ws + 576 * KB);
  int2*  se    = (int2*)(ws + 640 * KB);
  float* z   = (float*)(ws + 3 * MB);
  float* hl  = (float*)(ws + 11 * MB);
  bf16*  qb  = (bf16*)(ws + 19 * MB);
  bf16*  kb  = (bf16*)(ws + 23 * MB);
  bf16*  vb  = (bf16*)(ws + 27 * MB);
  float* ob  = (float*)(ws + 31 * MB);
  float* ha  = (float*)(ws + 39 * MB);
  float* hb  = (float*)(ws + 47 * MB);
  float* t1  = (float*)qb;                 // gin mid [N][128] (spans qb+kb; dead before qkv)
  float* ff1 = z;                          // [N][256] spans z..hl (16MB; both dead then)
  float* h2  = ob;                         // ff2 out reuses ob (ob dead after outproj)
  float* out = (float*)d_out;

  prep_k<<<708, 256, 0, stream>>>(gw1, gw2, ipw, opw, fw1, fw2, W, cnt, stats);
  edge_count_k<<<1024, 256, 0, stream>>>(ei, cnt);
  scan_k<<<1, 1024, 0, stream>>>(cnt, off, cur);
  edge_scatter_k<<<1024, 256, 0, stream>>>(ei, cur, se);
  aggr_k<<<4096, 256, 0, stream>>>(x, ea, off, se, z);
  // t1 = relu(z @ gin_w1 + b1)
  gemm_k<1, 1, true, 0, false, 0><<<512, 256, 0, stream>>>(
      z, W + 0, gb1, nullptr, t1, nullptr, nullptr, nullptr, nullptr);
  // hl = t1 @ gin_w2 + b2 + x   (+bn1l stats)
  gemm_k<1, 1, false, 1, true, 0><<<512, 256, 0, stream>>>(
      t1, W + 16384, gb2, x, hl, nullptr, nullptr, nullptr, stats + 0);
  // q,k,v = x @ in_proj_w.T + b  (bf16 out)
  gemm_k<3, 1, false, 0, false, 1><<<512, 256, 0, stream>>>(
      x, W + 32768, ipb, nullptr, nullptr, qb, kb, vb, nullptr);
  attn_k<<<512, 256, 0, stream>>>(qb, kb, vb, ob);
  // ha = o @ out_proj_w.T + b + x   (+bn1a stats)
  gemm_k<1, 1, false, 1, true, 0><<<512, 256, 0, stream>>>(
      ob, W + 81920, opb, x, ha, nullptr, nullptr, nullptr, stats + 256);
  combine_k<<<2048, 256, 0, stream>>>(hl, ha, stats, bn1l_g, bn1l_b, bn1a_g, bn1a_b, hb);
  // ff1 = relu(h @ ff_w1 + b1)   [N][256]
  gemm_k<2, 1, true, 0, false, 0><<<512, 256, 0, stream>>>(
      hb, W + 98304, fb1, nullptr, ff1, nullptr, nullptr, nullptr, nullptr);
  // h2 = ff1 @ ff_w2 + b2 + h   (+bn2 stats)
  gemm_k<1, 2, false, 1, true, 0><<<512, 256, 0, stream>>>(
      ff1, W + 131072, fb2, hb, h2, nullptr, nullptr, nullptr, stats + 512);
  apply_k<<<2048, 256, 0, stream>>>(h2, stats, bn2_g, bn2_b, out);
}